// Round 13
// baseline (227.318 us; speedup 1.0000x reference)
//
#include <hip/hip_runtime.h>

typedef __attribute__((ext_vector_type(8)))  _Float16 f16x8;
typedef __attribute__((ext_vector_type(4)))  _Float16 f16x4;
typedef __attribute__((ext_vector_type(2)))  __fp16   fp16x2;  // cvt_pkrtz return type
typedef __attribute__((ext_vector_type(4)))  float    f32x4;

#define TT 16384
#define KD 1024
#define ND 3072
#define NE 16
#define WSZ (NE * ND * KD)              // 50331648 elements (W only)
#define NEED_WS ((size_t)WSZ * 2)

#define BM 256
#define BN 256
#define BK 64
#define NSTEP (KD / BK)                 // 16
#define ROWB (BK * 2)                   // 128 B per LDS row (f16)

#define BAR() __builtin_amdgcn_s_barrier()
#define LGKM0_BAR() do {                                        \
    asm volatile("s_waitcnt lgkmcnt(0)" ::: "memory");          \
    __builtin_amdgcn_s_barrier();                               \
} while (0)
#define WAIT_VM(n) asm volatile("s_waitcnt vmcnt(" #n ")" ::: "memory")

// XOR swizzle: conflict-free ds_read_b128 column access on 128B rows (m201).
__device__ __forceinline__ int swz(int row, int kbyte) {
    return row * ROWB + (kbyte ^ ((row & 7) << 4));
}

__device__ __forceinline__ int find_expert(const void* cntp, int row0) {
    // JAX default config demotes int64 -> int32; detect which layout we got.
    const int* w = (const int*)cntp;
    int oddsum = 0;
    #pragma unroll
    for (int i = 1; i < 16; i += 2) oddsum |= w[i];
    int e = 0;
    long long cum = 0;
    if (oddsum == 0) {  // int64 counts
        const long long* c = (const long long*)cntp;
        #pragma unroll
        for (int i = 0; i < NE; ++i) { if ((long long)row0 >= cum) e = i; cum += c[i]; }
    } else {            // int32 counts
        #pragma unroll
        for (int i = 0; i < NE; ++i) { if ((long long)row0 >= cum) e = i; cum += w[i]; }
    }
    return e;
}

// Direct global->LDS DMA, 16B/lane. LDS dest = wave-uniform base + lane*16.
__device__ __forceinline__ void gl16(const void* g, void* l) {
    __builtin_amdgcn_global_load_lds(
        (const __attribute__((address_space(1))) unsigned int*)g,
        (__attribute__((address_space(3))) unsigned int*)l, 16, 0, 0);
}

// ---------------- pre-pass: fp32 -> f16, W ONLY (A fused into gemm) -------
// Non-temporal reads: fp32 W is dead after this pass; keep L3 biased toward
// the f16 output so the gemm's W16 reads are L3-hits.
__global__ __launch_bounds__(256) void cvt_w(const float* __restrict__ W,
                                             _Float16* __restrict__ dst) {
    size_t i = ((size_t)blockIdx.x * 256 + threadIdx.x) * 8;
    const float* src = W + i;
    f32x4 v0 = __builtin_nontemporal_load((const f32x4*)src);
    f32x4 v1 = __builtin_nontemporal_load((const f32x4*)(src + 4));
    f16x8 h;
    h[0] = (_Float16)v0[0]; h[1] = (_Float16)v0[1];
    h[2] = (_Float16)v0[2]; h[3] = (_Float16)v0[3];
    h[4] = (_Float16)v1[0]; h[5] = (_Float16)v1[1];
    h[6] = (_Float16)v1[2]; h[7] = (_Float16)v1[3];
    *(f16x8*)(dst + i) = h;
}

// 16 MFMA for quadrant (MH,NH) from fragment sets AF,BF (literal idx, rule #20)
#define MFMA16(AF, BF, MH, NH) do {                                          \
    __builtin_amdgcn_s_setprio(1);                                           \
    _Pragma("unroll")                                                        \
    for (int kk = 0; kk < 2; ++kk)                                           \
        _Pragma("unroll")                                                    \
        for (int m = 0; m < 4; ++m)                                          \
            _Pragma("unroll")                                                \
            for (int n = 0; n < 2; ++n)                                      \
                acc[MH][NH][m][n] = __builtin_amdgcn_mfma_f32_16x16x32_f16(  \
                    AF[kk][m], BF[kk][n], acc[MH][NH][m][n], 0, 0, 0);       \
    __builtin_amdgcn_s_setprio(0);                                           \
} while (0)

// ---------------- main GEMM: 4-window pipeline, A fused fp32->f16 ----------
// B path: gl16 (pre-swizzled source) as R11/R12. A path: fp32 reg-stage +
// cvt_pkrtz + swizzled ds_write_b64 (T14 issue-early/write-late). Quadrant
// order Q00,Q01 (af=A0) -> Q10,Q11 (af=A1) shares ONE af set (32 regs).
// vmcnt queue per window fully counted (never drains mid-loop); A ds_writes
// fenced by lgkmcnt(0)-before-barrier for cross-wave visibility.
__launch_bounds__(512, 2)
__global__ void gemm16(const float* __restrict__ A,
                       const void* __restrict__ cnt,
                       const _Float16* __restrict__ W16,
                       const float* __restrict__ bias,
                       float* __restrict__ Y) {
    __shared__ __align__(16) char Aslot[2][2][128 * ROWB];  // [half][parity]
    __shared__ __align__(16) char Bslot[2][2][128 * ROWB];  // 128 KiB total

    // T1: bijective XCD-aware swizzle (768 % 8 == 0)
    const int nwg = gridDim.x;
    const int bid0 = blockIdx.x;
    const int wgid = (bid0 & 7) * (nwg >> 3) + (bid0 >> 3);

    const int mt = wgid / (ND / BN);
    const int nt = wgid % (ND / BN);
    const int row0 = mt * BM;
    const int col0 = nt * BN;

    const int e = find_expert(cnt, row0);
    const _Float16* We = W16 + (size_t)e * ND * KD;

    const int tid = threadIdx.x;
    const int l = tid & 63;
    const int w = tid >> 6;   // wave 0..7
    const int wr = w >> 2;    // 0..1 : 64-row strip within each A-half
    const int wc = w & 3;     // 0..3 : 32-col strip within each B-half
    const int lr = l & 15;
    const int lk = l >> 4;

    // ---- B staging (gl16, pre-swizzled source; rule #21 both-sides) ----
    const int laneoff = ((l & 7) * 16) ^ ((l >> 3) << 4);
    const size_t bsrcoff = (size_t)(w * 16 + (l >> 3)) * (KD * 2) + laneoff;
    const char* gB0 = (const char*)We + (size_t)col0 * (KD * 2);
    const char* gB1 = gB0 + (size_t)128 * (KD * 2);

    auto stageB = [&](const char* ghalf, char* slot, int t) {
        const char* s = ghalf + t * 128 + bsrcoff;
        gl16(s,                slot + w * 2048);
        gl16(s + 8 * (KD * 2), slot + w * 2048 + 1024);
    };

    // ---- A staging (fp32 reg + cvt + swizzled ds_write_b64) ----
    // A-half = 128 rows x 64 K fp32; thread covers 4 f32x4 quads:
    // q = c*512+tid -> row q>>4, quad q&15 (coalesced: 16B/lane).
    int aoffA[4], aswz[4];
    #pragma unroll
    for (int c = 0; c < 4; ++c) {
        int q = c * 512 + tid;
        int r = q >> 4;
        int qd = q & 15;
        aoffA[c] = r * KD + qd * 4;          // element offset within half
        aswz[c]  = swz(r, qd * 8);           // f16 byte offset, swizzled
    }
    const float* gA0f = A + (size_t)row0 * KD;
    const float* gA1f = gA0f + (size_t)128 * KD;

    f32x4 rA0[4], rA1[4];
    auto issueA = [&](f32x4 (&rA)[4], const float* ghalf, int t) {
        const float* s = ghalf + t * 64;
        #pragma unroll
        for (int c = 0; c < 4; ++c) rA[c] = *(const f32x4*)(s + aoffA[c]);
    };
    auto writeA = [&](const f32x4 (&rA)[4], char* slot) {
        #pragma unroll
        for (int c = 0; c < 4; ++c) {
            union { f16x4 v; fp16x2 h[2]; } u;
            u.h[0] = __builtin_amdgcn_cvt_pkrtz(rA[c][0], rA[c][1]);
            u.h[1] = __builtin_amdgcn_cvt_pkrtz(rA[c][2], rA[c][3]);
            *(f16x4*)&slot[aswz[c]] = u.v;
        }
    };

    f32x4 acc[2][2][4][2] = {};   // [mh][nh][m][n] -> AGPR side
    f16x8 af[2][4], bf0[2][2], bf1[2][2];

    auto read_af = [&](const char* slot) {
        #pragma unroll
        for (int kk = 0; kk < 2; ++kk)
            #pragma unroll
            for (int m = 0; m < 4; ++m) {
                int r = wr * 64 + m * 16 + lr;
                af[kk][m] = *(const f16x8*)&slot[swz(r, kk * 64 + lk * 16)];
            }
    };
    auto read_bf = [&](f16x8 (&bf)[2][2], const char* slot) {
        #pragma unroll
        for (int kk = 0; kk < 2; ++kk)
            #pragma unroll
            for (int n = 0; n < 2; ++n) {
                int r = wc * 32 + n * 16 + lr;
                bf[kk][n] = *(const f16x8*)&slot[swz(r, kk * 64 + lk * 16)];
            }
    };

    // ---- Prologue: tile 0 fully staged (one-time drains allowed) ----
    issueA(rA0, gA0f, 0);                 // 4 vm
    stageB(gB0, &Bslot[0][0][0], 0);      // +2 = 6
    stageB(gB1, &Bslot[1][0][0], 0);      // +2 = 8
    WAIT_VM(4);                           // A0(0) done
    writeA(rA0, &Aslot[0][0][0]);
    issueA(rA1, gA1f, 0);                 // queue [B0 2, B1 2, A1 4] = 8
    WAIT_VM(0);                           // one-time drain
    writeA(rA1, &Aslot[1][0][0]);

    // ---- main loop t=0..14 (stages t+1) ----
    for (int t = 0; t < NSTEP - 1; ++t) {
        const int par = t & 1, nxt = par ^ 1;
        // w0: Q00. Reads A0(t),B0(t); issue A0(t+1) fp32 loads.
        LGKM0_BAR();                      // A1(t) write visible (prev w3)
        read_af(Aslot[0][par]);
        read_bf(bf0, Bslot[0][par]);
        issueA(rA0, gA0f, t + 1);         // out: [B1(t)2, A0'4] = 6
        MFMA16(af, bf0, 0, 0);
        // w1: Q01. Needs B1(t); stage B0(t+1).
        BAR();
        WAIT_VM(4);                       // B1(t) done -> [A0'4]
        read_bf(bf1, Bslot[1][par]);
        stageB(gB0, &Bslot[0][nxt][0], t + 1);   // [A0'4, B0'2] = 6
        MFMA16(af, bf1, 0, 1);
        // w2: Q10. Reads A1(t); issue A1(t+1); write A0(t+1).
        BAR();
        read_af(Aslot[1][par]);
        issueA(rA1, gA1f, t + 1);         // [A0'4, B0'2, A1'4] = 10
        WAIT_VM(6);                       // A0' done -> [B0'2, A1'4]
        writeA(rA0, &Aslot[0][nxt][0]);
        MFMA16(af, bf0, 1, 0);
        // w3: Q11. Stage B1(t+1); write A1(t+1). Never drains.
        LGKM0_BAR();                      // A0' write visible next tile
        stageB(gB1, &Bslot[1][nxt][0], t + 1);   // [B0'2, A1'4, B1'2] = 8
        WAIT_VM(2);                       // B0',A1' done -> [B1'2] invariant
        writeA(rA1, &Aslot[1][nxt][0]);
        MFMA16(af, bf1, 1, 1);
    }

    // ---- tail t=15: no staging; drain the last 2 gl16 ----
    {
        const int par = (NSTEP - 1) & 1;
        LGKM0_BAR();
        read_af(Aslot[0][par]);
        read_bf(bf0, Bslot[0][par]);
        MFMA16(af, bf0, 0, 0);
        BAR();
        WAIT_VM(0);                       // B1(15) done
        read_bf(bf1, Bslot[1][par]);
        MFMA16(af, bf1, 0, 1);
        BAR();
        read_af(Aslot[1][par]);
        MFMA16(af, bf0, 1, 0);
        MFMA16(af, bf1, 1, 1);
    }

    // Epilogue: 16x16 C/D layout col = lane&15, row = (lane>>4)*4 + j
    float bv[2][2];
    #pragma unroll
    for (int nh = 0; nh < 2; ++nh)
        #pragma unroll
        for (int n = 0; n < 2; ++n)
            bv[nh][n] = bias[(size_t)e * ND + col0 + nh * 128 + wc * 32 + n * 16 + lr];
    #pragma unroll
    for (int mh = 0; mh < 2; ++mh)
        #pragma unroll
        for (int nh = 0; nh < 2; ++nh)
            #pragma unroll
            for (int m = 0; m < 4; ++m)
                #pragma unroll
                for (int j = 0; j < 4; ++j) {
                    int r = row0 + mh * 128 + wr * 64 + m * 16 + lk * 4 + j;
                    float* yp = Y + (size_t)r * ND + col0 + nh * 128 + wc * 32 + lr;
                    yp[0]  = acc[mh][nh][m][0][j] + bv[nh][0];
                    yp[16] = acc[mh][nh][m][1][j] + bv[nh][1];
                }
}

// ---------------- fallback (R3-class 256^2 fp32 reg-staging) --------------
__launch_bounds__(512, 2)
__global__ void fallback_gemm(const float* __restrict__ A,
                              const void* __restrict__ cnt,
                              const float* __restrict__ W,
                              const float* __restrict__ bias,
                              float* __restrict__ Y) {
    __shared__ __align__(16) char ldsbuf[2][2][BM * ROWB];

    const int nwg = gridDim.x;
    const int bid0 = blockIdx.x;
    const int wgid = (bid0 & 7) * (nwg >> 3) + (bid0 >> 3);

    const int mt = wgid / (ND / BN);
    const int nt = wgid % (ND / BN);
    const int row0 = mt * BM;
    const int col0 = nt * BN;

    const int e = find_expert(cnt, row0);
    const float* We = W + (size_t)e * ND * KD;

    const int tid = threadIdx.x;
    const int lane = tid & 63;
    const int w = tid >> 6;
    const int wr = w >> 2;
    const int wc = w & 3;
    const int lr = lane & 15;
    const int lk = lane >> 4;

    int soff[4];
    size_t aoff[4], boff[4];
    #pragma unroll
    for (int c = 0; c < 4; ++c) {
        int q = c * 512 + tid;
        int r = q >> 3;
        int kb = (q & 7) * 8;
        soff[c] = swz(r, kb * 2);
        aoff[c] = (size_t)(row0 + r) * KD + kb;
        boff[c] = (size_t)(col0 + r) * KD + kb;
    }

    f32x4 ra[4][2], rb[4][2];

    auto load_regs = [&](int ks) {
        const int k0 = ks * BK;
        #pragma unroll
        for (int c = 0; c < 4; ++c) {
            const float* ap = A + aoff[c] + k0;
            ra[c][0] = *(const f32x4*)ap;
            ra[c][1] = *(const f32x4*)(ap + 4);
            const float* bp = We + boff[c] + k0;
            rb[c][0] = *(const f32x4*)bp;
            rb[c][1] = *(const f32x4*)(bp + 4);
        }
    };

    auto write_lds = [&](int buf) {
        #pragma unroll
        for (int c = 0; c < 4; ++c) {
            union { f16x8 v; fp16x2 h[4]; } ua, ub;
            ua.h[0] = __builtin_amdgcn_cvt_pkrtz(ra[c][0][0], ra[c][0][1]);
            ua.h[1] = __builtin_amdgcn_cvt_pkrtz(ra[c][0][2], ra[c][0][3]);
            ua.h[2] = __builtin_amdgcn_cvt_pkrtz(ra[c][1][0], ra[c][1][1]);
            ua.h[3] = __builtin_amdgcn_cvt_pkrtz(ra[c][1][2], ra[c][1][3]);
            ub.h[0] = __builtin_amdgcn_cvt_pkrtz(rb[c][0][0], rb[c][0][1]);
            ub.h[1] = __builtin_amdgcn_cvt_pkrtz(rb[c][0][2], rb[c][0][3]);
            ub.h[2] = __builtin_amdgcn_cvt_pkrtz(rb[c][1][0], rb[c][1][1]);
            ub.h[3] = __builtin_amdgcn_cvt_pkrtz(rb[c][1][2], rb[c][1][3]);
            *(f16x8*)&ldsbuf[buf][0][soff[c]] = ua.v;
            *(f16x8*)&ldsbuf[buf][1][soff[c]] = ub.v;
        }
    };

    f32x4 acc[8][4] = {};

    auto compute = [&](const char* Asb, const char* Bsb) {
        #pragma unroll
        for (int kk = 0; kk < 2; ++kk) {
            f16x8 af[8], bf[4];
            #pragma unroll
            for (int m = 0; m < 8; ++m) {
                int r = wr * 128 + m * 16 + lr;
                af[m] = *(const f16x8*)&Asb[swz(r, kk * 64 + lk * 16)];
            }
            #pragma unroll
            for (int n = 0; n < 4; ++n) {
                int r = wc * 64 + n * 16 + lr;
                bf[n] = *(const f16x8*)&Bsb[swz(r, kk * 64 + lk * 16)];
            }
            #pragma unroll
            for (int m = 0; m < 8; ++m)
                #pragma unroll
                for (int n = 0; n < 4; ++n)
                    acc[m][n] = __builtin_amdgcn_mfma_f32_16x16x32_f16(
                        af[m], bf[n], acc[m][n], 0, 0, 0);
        }
    };

    load_regs(0);
    write_lds(0);
    __syncthreads();

    for (int t = 0; t < NSTEP; ++t) {
        const int buf = t & 1;
        if (t + 1 < NSTEP) load_regs(t + 1);
        compute(ldsbuf[buf][0], ldsbuf[buf][1]);
        __syncthreads();
        if (t + 1 < NSTEP) write_lds(buf ^ 1);
        __syncthreads();
    }

    const int cb = col0 + wc * 64;
    const int rb0_ = row0 + wr * 128;
    float bv[4];
    #pragma unroll
    for (int n = 0; n < 4; ++n) bv[n] = bias[(size_t)e * ND + cb + n * 16 + lr];
    #pragma unroll
    for (int m = 0; m < 8; ++m) {
        #pragma unroll
        for (int j = 0; j < 4; ++j) {
            int r = rb0_ + m * 16 + lk * 4 + j;
            float* yp = Y + (size_t)r * ND + cb + lr;
            #pragma unroll
            for (int n = 0; n < 4; ++n)
                yp[n * 16] = acc[m][n][j] + bv[n];
        }
    }
}

extern "C" void kernel_launch(void* const* d_in, const int* in_sizes, int n_in,
                              void* d_out, int out_size, void* d_ws, size_t ws_size,
                              hipStream_t stream) {
    const float* inp  = (const float*)d_in[0];
    const void*  cnt  = d_in[1];               // int32 or int64, detected in-kernel
    const float* wgt  = (const float*)d_in[2];
    const float* bias = (const float*)d_in[3];
    float* out = (float*)d_out;

    dim3 grid((TT / BM) * (ND / BN));          // 64 * 12 = 768 blocks
    dim3 block(512);

    if (ws_size >= NEED_WS) {
        _Float16* w16 = (_Float16*)d_ws;
        cvt_w<<<dim3(WSZ / (8 * 256)), dim3(256), 0, stream>>>(wgt, w16);
        gemm16<<<grid, block, 0, stream>>>(inp, cnt, w16, bias, out);
    } else {
        fallback_gemm<<<grid, block, 0, stream>>>(inp, cnt, wgt, bias, out);
    }
}

// Round 14
// 193.979 us; speedup vs baseline: 1.1719x; 1.1719x over previous
//
#include <hip/hip_runtime.h>

typedef __attribute__((ext_vector_type(8)))  _Float16 f16x8;
typedef __attribute__((ext_vector_type(2)))  __fp16   fp16x2;  // cvt_pkrtz return type
typedef __attribute__((ext_vector_type(4)))  float    f32x4;

#define TT 16384
#define KD 1024
#define ND 3072
#define NE 16
#define ASZ (TT * KD)                   // 16777216 elements
#define WSZ (NE * ND * KD)              // 50331648 elements
#define NEED_WS ((size_t)(ASZ + WSZ) * 2)

#define BM 256
#define BN 256
#define BK 64
#define NSTEP (KD / BK)                 // 16
#define ROWB (BK * 2)                   // 128 B per LDS row (f16)

#define BAR() __builtin_amdgcn_s_barrier()
#define WAIT_VM(n) asm volatile("s_waitcnt vmcnt(" #n ")" ::: "memory")

// XOR swizzle: conflict-free ds_read_b128 column access on 128B rows (m201).
__device__ __forceinline__ int swz(int row, int kbyte) {
    return row * ROWB + (kbyte ^ ((row & 7) << 4));
}

__device__ __forceinline__ int find_expert(const void* cntp, int row0) {
    // JAX default config demotes int64 -> int32; detect which layout we got.
    const int* w = (const int*)cntp;
    int oddsum = 0;
    #pragma unroll
    for (int i = 1; i < 16; i += 2) oddsum |= w[i];
    int e = 0;
    long long cum = 0;
    if (oddsum == 0) {  // int64 counts
        const long long* c = (const long long*)cntp;
        #pragma unroll
        for (int i = 0; i < NE; ++i) { if ((long long)row0 >= cum) e = i; cum += c[i]; }
    } else {            // int32 counts
        #pragma unroll
        for (int i = 0; i < NE; ++i) { if ((long long)row0 >= cum) e = i; cum += w[i]; }
    }
    return e;
}

// Direct global->LDS DMA, 16B/lane. LDS dest = wave-uniform base + lane*16.
__device__ __forceinline__ void gl16(const void* g, void* l) {
    __builtin_amdgcn_global_load_lds(
        (const __attribute__((address_space(1))) unsigned int*)g,
        (__attribute__((address_space(3))) unsigned int*)l, 16, 0, 0);
}

// ---------------- pre-pass: fp32 -> f16 for A and W ----------------
__global__ __launch_bounds__(256) void cvt_kernel(const float* __restrict__ A,
                                                  const float* __restrict__ W,
                                                  _Float16* __restrict__ dst) {
    size_t i = ((size_t)blockIdx.x * 256 + threadIdx.x) * 8;
    const float* src = (i < (size_t)ASZ) ? (A + i) : (W + (i - ASZ));
    f32x4 v0 = *(const f32x4*)src;
    f32x4 v1 = *(const f32x4*)(src + 4);
    f16x8 h;
    h[0] = (_Float16)v0[0]; h[1] = (_Float16)v0[1];
    h[2] = (_Float16)v0[2]; h[3] = (_Float16)v0[3];
    h[4] = (_Float16)v1[0]; h[5] = (_Float16)v1[1];
    h[6] = (_Float16)v1[2]; h[7] = (_Float16)v1[3];
    *(f16x8*)(dst + i) = h;
}

// 16 MFMA for quadrant (MH,NH) from fragment sets AF,BF (literal idx, rule #20)
#define MFMA16(AF, BF, MH, NH) do {                                          \
    __builtin_amdgcn_s_setprio(1);                                           \
    _Pragma("unroll")                                                        \
    for (int kk = 0; kk < 2; ++kk)                                           \
        _Pragma("unroll")                                                    \
        for (int m = 0; m < 4; ++m)                                          \
            _Pragma("unroll")                                                \
            for (int n = 0; n < 2; ++n)                                      \
                acc[MH][NH][m][n] = __builtin_amdgcn_mfma_f32_16x16x32_f16(  \
                    AF[kk][m], BF[kk][n], acc[MH][NH][m][n], 0, 0, 0);       \
    __builtin_amdgcn_s_setprio(0);                                           \
} while (0)

// ---------------- main GEMM: 3-window read-ahead pipeline (R12, verified) --
// Slot ring A[2][2]/B[2][2] (half x parity); exact counted vmcnt (8->4,
// 6->4, 6->4 per window, never drains mid-loop); each window reads frags
// for the NEXT quadrant while MFMA-ing the CURRENT one.
__launch_bounds__(512, 2)
__global__ void gemm16(const _Float16* __restrict__ A16,
                       const void* __restrict__ cnt,
                       const _Float16* __restrict__ W16,
                       const float* __restrict__ bias,
                       float* __restrict__ Y) {
    __shared__ __align__(16) char Aslot[2][2][128 * ROWB];  // [half][parity]
    __shared__ __align__(16) char Bslot[2][2][128 * ROWB];  // 128 KiB total

    // T1: bijective XCD-aware swizzle (768 % 8 == 0)
    const int nwg = gridDim.x;
    const int bid0 = blockIdx.x;
    const int wgid = (bid0 & 7) * (nwg >> 3) + (bid0 >> 3);

    const int mt = wgid / (ND / BN);
    const int nt = wgid % (ND / BN);
    const int row0 = mt * BM;
    const int col0 = nt * BN;

    const int e = find_expert(cnt, row0);
    const _Float16* We = W16 + (size_t)e * ND * KD;

    const int tid = threadIdx.x;
    const int l = tid & 63;
    const int w = tid >> 6;   // wave 0..7
    const int wr = w >> 2;    // 0..1 : 64-row strip within each A-half
    const int wc = w & 3;     // 0..3 : 32-col strip within each B-half
    const int lr = l & 15;
    const int lk = l >> 4;

    // Staging: half-tile = 128 rows x 64 K f16 = 16 KiB = 2 gl16/thread.
    // Wave w covers rows [w*16, w*16+16). Source pre-swizzled (rule #21):
    // lane l -> row w*16+8i+(l>>3), byte ((l&7)*16)^((l>>3)<<4).
    const int laneoff = ((l & 7) * 16) ^ ((l >> 3) << 4);
    const size_t srcoff = (size_t)(w * 16 + (l >> 3)) * (KD * 2) + laneoff;

    const char* gA0 = (const char*)A16 + (size_t)row0 * (KD * 2);
    const char* gA1 = gA0 + (size_t)128 * (KD * 2);
    const char* gB0 = (const char*)We + (size_t)col0 * (KD * 2);
    const char* gB1 = gB0 + (size_t)128 * (KD * 2);

    auto stage_half = [&](const char* ghalf, char* slot, int t) {
        const char* s = ghalf + t * 128 + srcoff;
        gl16(s,                slot + w * 2048);
        gl16(s + 8 * (KD * 2), slot + w * 2048 + 1024);
    };

    f32x4 acc[2][2][4][2] = {};   // [mh][nh][m][n] -> AGPR side
    f16x8 af0[2][4], af1[2][4], bf0[2][2], bf1[2][2];

    auto read_A = [&](f16x8 (&af)[2][4], const char* slot) {
        #pragma unroll
        for (int kk = 0; kk < 2; ++kk)
            #pragma unroll
            for (int m = 0; m < 4; ++m) {
                int r = wr * 64 + m * 16 + lr;
                af[kk][m] = *(const f16x8*)&slot[swz(r, kk * 64 + lk * 16)];
            }
    };
    auto read_B = [&](f16x8 (&bf)[2][2], const char* slot) {
        #pragma unroll
        for (int kk = 0; kk < 2; ++kk)
            #pragma unroll
            for (int n = 0; n < 2; ++n) {
                int r = wc * 32 + n * 16 + lr;
                bf[kk][n] = *(const f16x8*)&slot[swz(r, kk * 64 + lk * 16)];
            }
    };

    // Prologue: tile 0's 4 half-tiles, in read-need order (A0,B0,A1,B1).
    stage_half(gA0, &Aslot[0][0][0], 0);
    stage_half(gB0, &Bslot[0][0][0], 0);
    stage_half(gA1, &Aslot[1][0][0], 0);
    stage_half(gB1, &Bslot[1][0][0], 0);

    // ---- t=0 peel (no Q11-of-prev to compute in w0) ----
    WAIT_VM(4);                       // A0,B0(0) done; A1,B1(0) in flight
    BAR();
    read_A(af0, Aslot[0][0]);
    read_B(bf0, Bslot[0][0]);
    stage_half(gA0, &Aslot[0][1][0], 1);
    WAIT_VM(4);                       // A1(0) done
    BAR();
    read_A(af1, Aslot[1][0]);
    stage_half(gB0, &Bslot[0][1][0], 1);
    MFMA16(af0, bf0, 0, 0);
    WAIT_VM(4);                       // B1(0) done
    BAR();
    read_B(bf1, Bslot[1][0]);
    stage_half(gA1, &Aslot[1][1][0], 1);
    MFMA16(af1, bf0, 1, 0);
    stage_half(gB1, &Bslot[1][1][0], 1);
    MFMA16(af0, bf1, 0, 1);

    // ---- main loop t=1..14: 3 windows, read-ahead-one-quadrant ----
    for (int t = 1; t < NSTEP - 1; ++t) {
        const int par = t & 1, nxt = par ^ 1;
        // w0: needs A0,B0(t). MFMA Q11 of tile t-1 (af1,bf1 still loaded).
        WAIT_VM(4);
        BAR();
        read_A(af0, Aslot[0][par]);
        read_B(bf0, Bslot[0][par]);
        stage_half(gA0, &Aslot[0][nxt][0], t + 1);
        MFMA16(af1, bf1, 1, 1);
        // w1: needs A1(t). MFMA Q00(t) (af0,bf0 read a full window ago).
        WAIT_VM(4);
        BAR();
        read_A(af1, Aslot[1][par]);
        stage_half(gB0, &Bslot[0][nxt][0], t + 1);
        MFMA16(af0, bf0, 0, 0);
        // w2 (merged): needs B1(t). MFMA Q10(t), then Q01(t).
        WAIT_VM(4);
        BAR();
        read_B(bf1, Bslot[1][par]);
        stage_half(gA1, &Aslot[1][nxt][0], t + 1);
        MFMA16(af1, bf0, 1, 0);
        stage_half(gB1, &Bslot[1][nxt][0], t + 1);
        MFMA16(af0, bf1, 0, 1);
    }

    // ---- t=15 tail: drain 4 -> 2 -> 0 ----
    {
        const int par = (NSTEP - 1) & 1;
        WAIT_VM(4);                   // A0,B0(15) done
        BAR();
        read_A(af0, Aslot[0][par]);
        read_B(bf0, Bslot[0][par]);
        MFMA16(af1, bf1, 1, 1);       // Q11(14)
        WAIT_VM(2);                   // A1(15) done
        BAR();
        read_A(af1, Aslot[1][par]);
        MFMA16(af0, bf0, 0, 0);
        WAIT_VM(0);                   // B1(15) done
        BAR();
        read_B(bf1, Bslot[1][par]);
        MFMA16(af1, bf0, 1, 0);
        MFMA16(af0, bf1, 0, 1);
        MFMA16(af1, bf1, 1, 1);
    }

    // Epilogue: 16x16 C/D layout col = lane&15, row = (lane>>4)*4 + j
    float bv[2][2];
    #pragma unroll
    for (int nh = 0; nh < 2; ++nh)
        #pragma unroll
        for (int n = 0; n < 2; ++n)
            bv[nh][n] = bias[(size_t)e * ND + col0 + nh * 128 + wc * 32 + n * 16 + lr];
    #pragma unroll
    for (int mh = 0; mh < 2; ++mh)
        #pragma unroll
        for (int nh = 0; nh < 2; ++nh)
            #pragma unroll
            for (int m = 0; m < 4; ++m)
                #pragma unroll
                for (int j = 0; j < 4; ++j) {
                    int r = row0 + mh * 128 + wr * 64 + m * 16 + lk * 4 + j;
                    float* yp = Y + (size_t)r * ND + col0 + nh * 128 + wc * 32 + lr;
                    yp[0]  = acc[mh][nh][m][0][j] + bv[nh][0];
                    yp[16] = acc[mh][nh][m][1][j] + bv[nh][1];
                }
}

// ---------------- fallback (R3-class 256^2 reg-staging, known-good) -------
__launch_bounds__(512, 2)
__global__ void fallback_gemm(const float* __restrict__ A,
                              const void* __restrict__ cnt,
                              const float* __restrict__ W,
                              const float* __restrict__ bias,
                              float* __restrict__ Y) {
    __shared__ __align__(16) char ldsbuf[2][2][BM * ROWB];

    const int nwg = gridDim.x;
    const int bid0 = blockIdx.x;
    const int wgid = (bid0 & 7) * (nwg >> 3) + (bid0 >> 3);

    const int mt = wgid / (ND / BN);
    const int nt = wgid % (ND / BN);
    const int row0 = mt * BM;
    const int col0 = nt * BN;

    const int e = find_expert(cnt, row0);
    const float* We = W + (size_t)e * ND * KD;

    const int tid = threadIdx.x;
    const int lane = tid & 63;
    const int w = tid >> 6;
    const int wr = w >> 2;
    const int wc = w & 3;
    const int lr = lane & 15;
    const int lk = lane >> 4;

    int soff[4];
    size_t aoff[4], boff[4];
    #pragma unroll
    for (int c = 0; c < 4; ++c) {
        int q = c * 512 + tid;
        int r = q >> 3;
        int kb = (q & 7) * 8;
        soff[c] = swz(r, kb * 2);
        aoff[c] = (size_t)(row0 + r) * KD + kb;
        boff[c] = (size_t)(col0 + r) * KD + kb;
    }

    f32x4 ra[4][2], rb[4][2];

    auto load_regs = [&](int ks) {
        const int k0 = ks * BK;
        #pragma unroll
        for (int c = 0; c < 4; ++c) {
            const float* ap = A + aoff[c] + k0;
            ra[c][0] = *(const f32x4*)ap;
            ra[c][1] = *(const f32x4*)(ap + 4);
            const float* bp = We + boff[c] + k0;
            rb[c][0] = *(const f32x4*)bp;
            rb[c][1] = *(const f32x4*)(bp + 4);
        }
    };

    auto write_lds = [&](int buf) {
        #pragma unroll
        for (int c = 0; c < 4; ++c) {
            union { f16x8 v; fp16x2 h[4]; } ua, ub;
            ua.h[0] = __builtin_amdgcn_cvt_pkrtz(ra[c][0][0], ra[c][0][1]);
            ua.h[1] = __builtin_amdgcn_cvt_pkrtz(ra[c][0][2], ra[c][0][3]);
            ua.h[2] = __builtin_amdgcn_cvt_pkrtz(ra[c][1][0], ra[c][1][1]);
            ua.h[3] = __builtin_amdgcn_cvt_pkrtz(ra[c][1][2], ra[c][1][3]);
            ub.h[0] = __builtin_amdgcn_cvt_pkrtz(rb[c][0][0], rb[c][0][1]);
            ub.h[1] = __builtin_amdgcn_cvt_pkrtz(rb[c][0][2], rb[c][0][3]);
            ub.h[2] = __builtin_amdgcn_cvt_pkrtz(rb[c][1][0], rb[c][1][1]);
            ub.h[3] = __builtin_amdgcn_cvt_pkrtz(rb[c][1][2], rb[c][1][3]);
            *(f16x8*)&ldsbuf[buf][0][soff[c]] = ua.v;
            *(f16x8*)&ldsbuf[buf][1][soff[c]] = ub.v;
        }
    };

    f32x4 acc[8][4] = {};

    auto compute = [&](const char* Asb, const char* Bsb) {
        #pragma unroll
        for (int kk = 0; kk < 2; ++kk) {
            f16x8 af[8], bf[4];
            #pragma unroll
            for (int m = 0; m < 8; ++m) {
                int r = wr * 128 + m * 16 + lr;
                af[m] = *(const f16x8*)&Asb[swz(r, kk * 64 + lk * 16)];
            }
            #pragma unroll
            for (int n = 0; n < 4; ++n) {
                int r = wc * 64 + n * 16 + lr;
                bf[n] = *(const f16x8*)&Bsb[swz(r, kk * 64 + lk * 16)];
            }
            #pragma unroll
            for (int m = 0; m < 8; ++m)
                #pragma unroll
                for (int n = 0; n < 4; ++n)
                    acc[m][n] = __builtin_amdgcn_mfma_f32_16x16x32_f16(
                        af[m], bf[n], acc[m][n], 0, 0, 0);
        }
    };

    load_regs(0);
    write_lds(0);
    __syncthreads();

    for (int t = 0; t < NSTEP; ++t) {
        const int buf = t & 1;
        if (t + 1 < NSTEP) load_regs(t + 1);
        compute(ldsbuf[buf][0], ldsbuf[buf][1]);
        __syncthreads();
        if (t + 1 < NSTEP) write_lds(buf ^ 1);
        __syncthreads();
    }

    const int cb = col0 + wc * 64;
    const int rb0_ = row0 + wr * 128;
    float bv[4];
    #pragma unroll
    for (int n = 0; n < 4; ++n) bv[n] = bias[(size_t)e * ND + cb + n * 16 + lr];
    #pragma unroll
    for (int m = 0; m < 8; ++m) {
        #pragma unroll
        for (int j = 0; j < 4; ++j) {
            int r = rb0_ + m * 16 + lk * 4 + j;
            float* yp = Y + (size_t)r * ND + cb + lr;
            #pragma unroll
            for (int n = 0; n < 4; ++n)
                yp[n * 16] = acc[m][n][j] + bv[n];
        }
    }
}

extern "C" void kernel_launch(void* const* d_in, const int* in_sizes, int n_in,
                              void* d_out, int out_size, void* d_ws, size_t ws_size,
                              hipStream_t stream) {
    const float* inp  = (const float*)d_in[0];
    const void*  cnt  = d_in[1];               // int32 or int64, detected in-kernel
    const float* wgt  = (const float*)d_in[2];
    const float* bias = (const float*)d_in[3];
    float* out = (float*)d_out;

    dim3 grid((TT / BM) * (ND / BN));          // 64 * 12 = 768 blocks
    dim3 block(512);

    if (ws_size >= NEED_WS) {
        _Float16* ws16 = (_Float16*)d_ws;
        cvt_kernel<<<dim3((ASZ + WSZ) / (8 * 256)), dim3(256), 0, stream>>>(inp, wgt, ws16);
        gemm16<<<grid, block, 0, stream>>>(ws16, cnt, ws16 + ASZ, bias, out);
    } else {
        fallback_gemm<<<grid, block, 0, stream>>>(inp, cnt, wgt, bias, out);
    }
}